// Round 1
// 141.795 us; speedup vs baseline: 1.1601x; 1.1601x over previous
//
#include <hip/hip_runtime.h>
#include <stdint.h>

// Problem constants (reference: N=4, L=4096, S=4096, H=8, D=64, fp32 in/out)
#define NB   4
#define LQ   4096
#define SK   4096
#define NHD  8
#define DD   64
#define ROWSTRIDE (NHD * DD)      // 512 floats between consecutive s (or l) rows
#define CH   16                   // S-chunks per (n,h)
#define SROWS (SK / CH)           // 256 rows per chunk
#define KVSZ (DD * DD)            // 4096
#define PART_STRIDE (KVSZ + DD)   // 4160: KV + Ksum
#define NHTOT (NB * NHD)          // 32
#define LT   64                   // L rows per k3 block
#define EPSF 1e-6f

typedef __attribute__((ext_vector_type(8))) short bf16x8;   // 8 bf16 (4 VGPRs)
typedef __attribute__((ext_vector_type(4))) float f32x4;

union FragU { uint32_t u[4]; bf16x8 v; };

__device__ __forceinline__ float fmap(float x) {
    // elu(x) + 1 == x+1 (x>0) else exp(x)
    return x > 0.f ? x + 1.f : __expf(x);
}

// Truncating hi/lo split of 8 f32 into two bf16x8 fragments.
// hi = trunc_bf16(x); lo = trunc_bf16(x - hi). x ~= hi + lo with rel err ~2^-16.
__device__ __forceinline__ void split8(const float* x, bf16x8& hi, bf16x8& lo) {
    FragU H, L;
#pragma unroll
    for (int p = 0; p < 4; ++p) {
        float a = x[2*p], b = x[2*p+1];
        uint32_t ua = __float_as_uint(a), ub = __float_as_uint(b);
        float ra = a - __uint_as_float(ua & 0xFFFF0000u);   // exact residual
        float rb = b - __uint_as_float(ub & 0xFFFF0000u);
        H.u[p] = (ua >> 16) | (ub & 0xFFFF0000u);
        L.u[p] = (__float_as_uint(ra) >> 16) | (__float_as_uint(rb) & 0xFFFF0000u);
    }
    hi = H.v; lo = L.v;
}

// ---------------------------------------------------------------------------
// k1: partial KV[d][e] = sum_s K~[s][d]*V[s][e]  and  Ksum[d] = sum_s K~[s][d]
// MFMA version, no LDS, no barriers. grid: NHTOT*CH blocks, 256 threads.
// Wave w handles m-tiles {2wm,2wm+1} x n-tiles {2wn,2wn+1} of the 64x64 C.
// Fragment source-k bijection M(i,g) = 16*(i>>2) + 4g + (i&3), identical for
// A and B -> result independent of HW k-layout.
// ---------------------------------------------------------------------------
__global__ __launch_bounds__(256) void k1_kv(const float* __restrict__ Kin,
                                             const float* __restrict__ Vin,
                                             float* __restrict__ part) {
    const int blk   = blockIdx.x;
    const int nh    = blk / CH;
    const int chunk = blk % CH;
    const int n = nh / NHD, h = nh % NHD;
    const int t = threadIdx.x;
    const int w = t >> 6, lane = t & 63;
    const int g = lane >> 4, r = lane & 15;
    const int wm = w & 1, wn = w >> 1;

    const size_t base = ((size_t)n * SK + (size_t)chunk * SROWS) * ROWSTRIDE
                        + (size_t)h * DD;

    const f32x4 zero4 = {0.f, 0.f, 0.f, 0.f};
    f32x4 acc[2][2] = {{zero4, zero4}, {zero4, zero4}};
    float ks[2] = {0.f, 0.f};

    for (int s0 = 0; s0 < SROWS; s0 += 32) {
        float xa[2][8], xb[2][8];
#pragma unroll
        for (int i = 0; i < 8; ++i) {
            const int soff = ((i & 4) << 2) + 4 * g + (i & 3);   // M(i,g)
            const size_t rowb = base + (size_t)(s0 + soff) * ROWSTRIDE;
#pragma unroll
            for (int mt = 0; mt < 2; ++mt)
                xa[mt][i] = Kin[rowb + (wm*2 + mt)*16 + r];
#pragma unroll
            for (int nt = 0; nt < 2; ++nt)
                xb[nt][i] = Vin[rowb + (wn*2 + nt)*16 + r];
        }
        bf16x8 ahi[2], alo[2], bhi[2], blo[2];
#pragma unroll
        for (int mt = 0; mt < 2; ++mt) {
#pragma unroll
            for (int i = 0; i < 8; ++i) xa[mt][i] = fmap(xa[mt][i]);
            if (wn == 0) {          // wave-uniform; avoid double-count (2x dup)
#pragma unroll
                for (int i = 0; i < 8; ++i) ks[mt] += xa[mt][i];
            }
            split8(xa[mt], ahi[mt], alo[mt]);
        }
#pragma unroll
        for (int nt = 0; nt < 2; ++nt) split8(xb[nt], bhi[nt], blo[nt]);
#pragma unroll
        for (int mt = 0; mt < 2; ++mt)
#pragma unroll
            for (int nt = 0; nt < 2; ++nt) {
                acc[mt][nt] = __builtin_amdgcn_mfma_f32_16x16x32_bf16(
                                  ahi[mt], bhi[nt], acc[mt][nt], 0, 0, 0);
                acc[mt][nt] = __builtin_amdgcn_mfma_f32_16x16x32_bf16(
                                  alo[mt], bhi[nt], acc[mt][nt], 0, 0, 0);
                acc[mt][nt] = __builtin_amdgcn_mfma_f32_16x16x32_bf16(
                                  ahi[mt], blo[nt], acc[mt][nt], 0, 0, 0);
            }
    }

    float* pb = part + ((size_t)nh * CH + chunk) * PART_STRIDE;
    // C mapping (m89-verified): col = lane&15, row = 4*(lane>>4) + reg
#pragma unroll
    for (int mt = 0; mt < 2; ++mt) {
        const int dbase = (wm*2 + mt)*16 + 4*g;
#pragma unroll
        for (int nt = 0; nt < 2; ++nt) {
            const int e = (wn*2 + nt)*16 + r;
#pragma unroll
            for (int j = 0; j < 4; ++j)
                pb[(dbase + j) * DD + e] = acc[mt][nt][j];
        }
    }
    if (wn == 0) {
#pragma unroll
        for (int mt = 0; mt < 2; ++mt) {
            float v = ks[mt];
            v += __shfl_xor(v, 16);
            v += __shfl_xor(v, 32);
            if (lane < 16) pb[KVSZ + (wm*2 + mt)*16 + lane] = v;
        }
    }
}

// ---------------------------------------------------------------------------
// k2: sum CH partials -> final [nh][4160]  (unchanged)
// ---------------------------------------------------------------------------
__global__ __launch_bounds__(256) void k2_reduce(const float* __restrict__ part,
                                                 float* __restrict__ fin) {
    const int idx = blockIdx.x * 256 + threadIdx.x;
    if (idx >= NHTOT * PART_STRIDE) return;
    const int nh = idx / PART_STRIDE;
    const int j  = idx - nh * PART_STRIDE;
    const float* p = part + (size_t)nh * CH * PART_STRIDE + j;
    float s = 0.f;
#pragma unroll
    for (int cix = 0; cix < CH; ++cix) s += p[(size_t)cix * PART_STRIDE];
    fin[idx] = s;
}

// ---------------------------------------------------------------------------
// k3: out[l][e] = (sum_d Q~[l][d]*KV[d][e]) / (sum_d Q~[l][d]*Ksum[d] + eps)
// MFMA version. KV staged once per block into LDS as pre-split bf16 hi/lo,
// transposed to [e][k'] with column permutation k'(d) s.t. each B fragment is
// one aligned ds_read_b128, plus (e&3)<<3 XOR swizzle for staging writes.
// z stays fully fp32. grid: NHTOT*64 blocks, 256 threads (wave w = 16 l-rows).
// ---------------------------------------------------------------------------
#define KVSTR 72   // bf16 row stride: 144 B, keeps b128 reads aligned, ~2-way banks

__global__ __launch_bounds__(256) void k3_out(const float* __restrict__ Qin,
                                              const float* __restrict__ fin,
                                              float* __restrict__ out) {
    const int blk = blockIdx.x;
    const int nh  = blk >> 6;
    const int lc  = blk & 63;
    const int n = nh >> 3, h = nh & 7;
    const int t = threadIdx.x;
    const int w = t >> 6, lane = t & 63;
    const int g = lane >> 4, r = lane & 15;

    __shared__ __align__(16) short KThi[DD][KVSTR];
    __shared__ __align__(16) short KTlo[DD][KVSTR];
    __shared__ __align__(16) float Ksm[DD];

    const float* fb = fin + (size_t)nh * PART_STRIDE;
    {
        // stage: lane e = t&63, quarter dq = t>>6 covers d = 16*dq .. 16*dq+15
        const int e  = t & 63;
        const int dq = t >> 6;
#pragma unroll
        for (int dd = 0; dd < 16; ++dd) {
            const int d = dq * 16 + dd;
            const float x = fb[d * DD + e];
            // k'(d): bits [d5][d3 d2][d4][d1 d0]  (bijection), then e-swizzle
            const int col = (((d & 32) | (d & 3) | (((d >> 4) & 1) << 2)
                              | (((d >> 2) & 3) << 3)) ^ ((e & 3) << 3));
            const uint32_t ux = __float_as_uint(x);
            const float lo = x - __uint_as_float(ux & 0xFFFF0000u);
            KThi[e][col] = (short)(ux >> 16);
            KTlo[e][col] = (short)(__float_as_uint(lo) >> 16);
        }
        if (t < DD) Ksm[t] = fb[KVSZ + t];
    }
    __syncthreads();

    const size_t qrow = (size_t)n * LQ + (size_t)lc * LT + w * 16 + r;
    const float* qp = Qin + qrow * ROWSTRIDE + (size_t)h * DD;

    const f32x4 zero4 = {0.f, 0.f, 0.f, 0.f};
    f32x4 acc[4] = {zero4, zero4, zero4, zero4};
    float z = 0.f;

#pragma unroll
    for (int kst = 0; kst < 2; ++kst) {
        const int kb = kst * 32;
        // A fragment: Q row r of this wave's tile, k = kb + M(i,g) — contiguous
        const float4 qa = *(const float4*)(qp + kb + 4*g);
        const float4 qb = *(const float4*)(qp + kb + 16 + 4*g);
        float qv[8] = {fmap(qa.x), fmap(qa.y), fmap(qa.z), fmap(qa.w),
                       fmap(qb.x), fmap(qb.y), fmap(qb.z), fmap(qb.w)};
        // z partial in full fp32 against fp32 Ksum (same k indices)
        const float4 ka = *(const float4*)&Ksm[kb + 4*g];
        const float4 kc = *(const float4*)&Ksm[kb + 16 + 4*g];
        z += qv[0]*ka.x + qv[1]*ka.y + qv[2]*ka.z + qv[3]*ka.w
           + qv[4]*kc.x + qv[5]*kc.y + qv[6]*kc.z + qv[7]*kc.w;
        bf16x8 ahi, alo;
        split8(qv, ahi, alo);
        const int cswz = 8 * (g ^ (r & 3));   // undo staging swizzle (e&3 == r&3)
#pragma unroll
        for (int nt = 0; nt < 4; ++nt) {
            const int e = nt*16 + r;
            const bf16x8 bh = *(const bf16x8*)&KThi[e][kb + cswz];
            const bf16x8 bl = *(const bf16x8*)&KTlo[e][kb + cswz];
            acc[nt] = __builtin_amdgcn_mfma_f32_16x16x32_bf16(ahi, bh, acc[nt], 0,0,0);
            acc[nt] = __builtin_amdgcn_mfma_f32_16x16x32_bf16(alo, bh, acc[nt], 0,0,0);
            acc[nt] = __builtin_amdgcn_mfma_f32_16x16x32_bf16(ahi, bl, acc[nt], 0,0,0);
        }
    }

    // z: sum over g-groups -> every lane holds full z for its A-row r
    z += __shfl_xor(z, 16);
    z += __shfl_xor(z, 32);

    const size_t obase0 = ((size_t)n * LQ + (size_t)lc * LT + w * 16) * ROWSTRIDE
                          + (size_t)h * DD;
#pragma unroll
    for (int j = 0; j < 4; ++j) {
        // C row = 4g + j; its z lives in lane (4g+j) (lanes 0..15 hold r==lane)
        const float zj = __shfl(z, 4*g + j);
        const float zi = 1.f / (zj + EPSF);
        const size_t ob = obase0 + (size_t)(4*g + j) * ROWSTRIDE;
#pragma unroll
        for (int nt = 0; nt < 4; ++nt)
            out[ob + nt*16 + r] = acc[nt][j] * zi;
    }
}

// ---------------------------------------------------------------------------
extern "C" void kernel_launch(void* const* d_in, const int* in_sizes, int n_in,
                              void* d_out, int out_size, void* d_ws, size_t ws_size,
                              hipStream_t stream) {
    const float* Q = (const float*)d_in[0];
    const float* K = (const float*)d_in[1];
    const float* V = (const float*)d_in[2];
    float* out = (float*)d_out;

    float* ws   = (float*)d_ws;
    float* part = ws;                                        // 512*4160 floats
    float* fin  = ws + (size_t)NHTOT * CH * PART_STRIDE;     // 32*4160 floats

    k1_kv<<<NHTOT * CH, 256, 0, stream>>>(K, V, part);
    k2_reduce<<<(NHTOT * PART_STRIDE + 255) / 256, 256, 0, stream>>>(part, fin);
    k3_out<<<NHTOT * (LQ / LT), 256, 0, stream>>>(Q, fin, out);
}